// Round 1
// baseline (468.252 us; speedup 1.0000x reference)
//
#include <hip/hip_runtime.h>
#include <hip/hip_bf16.h>
#include <math.h>

#define N 8192
#define D 1024
#define C 1000
#define CP 1024
#define INV_T (1.0f / 0.3f)

typedef __bf16 bf16_t;
typedef bf16_t bf16x8 __attribute__((ext_vector_type(8)));
typedef float f32x4 __attribute__((ext_vector_type(4)));

// ---------------- normalize: feat -> feat_n (bf16), norms (f32) ----------------
__global__ void normalize_kernel(const float* __restrict__ feat,
                                 float* __restrict__ norms,
                                 bf16_t* __restrict__ feat_n) {
  int row = blockIdx.x;
  int t = threadIdx.x;  // 256 threads, each handles 4 consecutive floats
  const float4* fr = (const float4*)(feat + (size_t)row * D);
  float4 x = fr[t];
  float ss = x.x * x.x + x.y * x.y + x.z * x.z + x.w * x.w;
  for (int off = 32; off; off >>= 1) ss += __shfl_down(ss, off, 64);
  __shared__ float sred[4];
  __shared__ float srn;
  int lane = t & 63, w = t >> 6;
  if (lane == 0) sred[w] = ss;
  __syncthreads();
  if (t == 0) {
    float tot = sred[0] + sred[1] + sred[2] + sred[3];
    float nrm = sqrtf(tot);
    norms[row] = nrm;
    srn = 1.0f / nrm;
  }
  __syncthreads();
  float rn = srn;
  union { bf16_t h[4]; uint2 u; } pk;
  pk.h[0] = (bf16_t)(x.x * rn);
  pk.h[1] = (bf16_t)(x.y * rn);
  pk.h[2] = (bf16_t)(x.z * rn);
  pk.h[3] = (bf16_t)(x.w * rn);
  *(uint2*)(feat_n + (size_t)row * D + t * 4) = pk.u;
}

// ---------------- cast W (f32 [C,D]) -> Wp (bf16 [CP,D], zero-padded) ----------------
__global__ void castw_kernel(const float* __restrict__ W, bf16_t* __restrict__ Wp) {
  int idx = blockIdx.x * 256 + threadIdx.x;  // CP*256 total, 4 cols each
  int row = idx >> 8;
  int c4 = (idx & 255) << 2;
  union { bf16_t h[4]; uint2 u; } pk;
  if (row < C) {
    float4 x = ((const float4*)(W + (size_t)row * D))[idx & 255];
    pk.h[0] = (bf16_t)x.x; pk.h[1] = (bf16_t)x.y;
    pk.h[2] = (bf16_t)x.z; pk.h[3] = (bf16_t)x.w;
  } else {
    pk.h[0] = pk.h[1] = pk.h[2] = pk.h[3] = (bf16_t)0.0f;
  }
  *(uint2*)(Wp + (size_t)row * D + c4) = pk.u;
}

// ---------------- label histogram ----------------
__global__ void hist_kernel(const int* __restrict__ labels, int* __restrict__ hist) {
  int i = blockIdx.x * 256 + threadIdx.x;
  if (i < N) atomicAdd(&hist[labels[i]], 1);
}

// ---------------- GEMM tile geometry ----------------
#define BM 128
#define BN 128
#define BK 32
#define BKP 40  // +8 bf16 pad: row stride 80B = 20 words -> 2-way bank aliasing (free)

// logits[i,c] = norms[i] * (feat_n[i,:] . Wp[c,:]) + b[c]
__launch_bounds__(256)
__global__ void logits_gemm(const bf16_t* __restrict__ A, const bf16_t* __restrict__ B,
                            const float* __restrict__ norms, const float* __restrict__ bias,
                            float* __restrict__ out) {
  __shared__ __align__(16) bf16_t As[BM * BKP];
  __shared__ __align__(16) bf16_t Bs[BN * BKP];
  int tileM = blockIdx.x * BM;
  int tileN = blockIdx.y * BN;
  int t = threadIdx.x;
  int lane = t & 63;
  int wave = t >> 6;
  int wm = (wave & 1) << 6;
  int wn = (wave >> 1) << 6;
  int l15 = lane & 15;
  int quad = lane >> 4;
  f32x4 acc[4][4] = {};
  int lrow = t >> 2;
  int lcol = (t & 3) << 3;
  for (int k0 = 0; k0 < D; k0 += BK) {
    *(int4*)(&As[lrow * BKP + lcol])        = *(const int4*)(&A[(size_t)(tileM + lrow) * D + k0 + lcol]);
    *(int4*)(&As[(lrow + 64) * BKP + lcol]) = *(const int4*)(&A[(size_t)(tileM + lrow + 64) * D + k0 + lcol]);
    *(int4*)(&Bs[lrow * BKP + lcol])        = *(const int4*)(&B[(size_t)(tileN + lrow) * D + k0 + lcol]);
    *(int4*)(&Bs[(lrow + 64) * BKP + lcol]) = *(const int4*)(&B[(size_t)(tileN + lrow + 64) * D + k0 + lcol]);
    __syncthreads();
    bf16x8 af[4], bf[4];
    for (int i = 0; i < 4; i++) af[i] = *(const bf16x8*)(&As[(wm + i * 16 + l15) * BKP + quad * 8]);
    for (int j = 0; j < 4; j++) bf[j] = *(const bf16x8*)(&Bs[(wn + j * 16 + l15) * BKP + quad * 8]);
    for (int i = 0; i < 4; i++)
      for (int j = 0; j < 4; j++)
        acc[i][j] = __builtin_amdgcn_mfma_f32_16x16x32_bf16(af[i], bf[j], acc[i][j], 0, 0, 0);
    __syncthreads();
  }
  for (int i = 0; i < 4; i++) {
    for (int r = 0; r < 4; r++) {
      int gr = tileM + wm + i * 16 + quad * 4 + r;
      float nrm = norms[gr];
      for (int j = 0; j < 4; j++) {
        int gc = tileN + wn + j * 16 + l15;
        if (gc < C) out[(size_t)gr * C + gc] = nrm * acc[i][j][r] + bias[gc];
      }
    }
  }
}

// sim tile = (feat_n @ feat_n^T)/t ; fused row reductions:
//   S[i] += sum_{j != i} exp(sim_ij) ; P[i] += sum_{j: lbl==, j!=i} sim_ij
__launch_bounds__(256)
__global__ void sim_gemm(const bf16_t* __restrict__ A, const int* __restrict__ labels,
                         float* __restrict__ S, float* __restrict__ P) {
  __shared__ __align__(16) bf16_t As[BM * BKP];
  __shared__ __align__(16) bf16_t Bs[BN * BKP];
  int tileM = blockIdx.x * BM;
  int tileN = blockIdx.y * BN;
  int t = threadIdx.x;
  int lane = t & 63;
  int wave = t >> 6;
  int wm = (wave & 1) << 6;
  int wn = (wave >> 1) << 6;
  int l15 = lane & 15;
  int quad = lane >> 4;
  f32x4 acc[4][4] = {};
  int lrow = t >> 2;
  int lcol = (t & 3) << 3;
  for (int k0 = 0; k0 < D; k0 += BK) {
    *(int4*)(&As[lrow * BKP + lcol])        = *(const int4*)(&A[(size_t)(tileM + lrow) * D + k0 + lcol]);
    *(int4*)(&As[(lrow + 64) * BKP + lcol]) = *(const int4*)(&A[(size_t)(tileM + lrow + 64) * D + k0 + lcol]);
    *(int4*)(&Bs[lrow * BKP + lcol])        = *(const int4*)(&A[(size_t)(tileN + lrow) * D + k0 + lcol]);
    *(int4*)(&Bs[(lrow + 64) * BKP + lcol]) = *(const int4*)(&A[(size_t)(tileN + lrow + 64) * D + k0 + lcol]);
    __syncthreads();
    bf16x8 af[4], bf[4];
    for (int i = 0; i < 4; i++) af[i] = *(const bf16x8*)(&As[(wm + i * 16 + l15) * BKP + quad * 8]);
    for (int j = 0; j < 4; j++) bf[j] = *(const bf16x8*)(&Bs[(wn + j * 16 + l15) * BKP + quad * 8]);
    for (int i = 0; i < 4; i++)
      for (int j = 0; j < 4; j++)
        acc[i][j] = __builtin_amdgcn_mfma_f32_16x16x32_bf16(af[i], bf[j], acc[i][j], 0, 0, 0);
    __syncthreads();
  }
  // fused epilogue: per-row exp-sum (excl. diagonal) + positive sim-sum
  int gcj[4], lc[4];
  for (int j = 0; j < 4; j++) {
    gcj[j] = tileN + wn + j * 16 + l15;
    lc[j] = labels[gcj[j]];
  }
  for (int i = 0; i < 4; i++) {
    for (int r = 0; r < 4; r++) {
      int gr = tileM + wm + i * 16 + quad * 4 + r;
      int lr = labels[gr];
      float ssum = 0.0f, psum = 0.0f;
      for (int j = 0; j < 4; j++) {
        float sim = acc[i][j][r] * INV_T;
        if (gcj[j] != gr) {
          ssum += __expf(sim);
          if (lc[j] == lr) psum += sim;
        }
      }
      // reduce across the 16 column-lanes of this quad (xor over bits 0-3)
      for (int m = 1; m < 16; m <<= 1) {
        ssum += __shfl_xor(ssum, m, 64);
        psum += __shfl_xor(psum, m, 64);
      }
      if (l15 == 0) {
        atomicAdd(&S[gr], ssum);
        atomicAdd(&P[gr], psum);
      }
    }
  }
}

// ---------------- CE: per-row logsumexp - label logit, atomically summed ----------------
__global__ void ce_kernel(const float* __restrict__ logits, const int* __restrict__ labels,
                          float* __restrict__ accums) {
  int row = blockIdx.x;
  const float* lr = logits + (size_t)row * C;
  int t = threadIdx.x;
  float s = 0.0f;
  for (int c = t; c < C; c += 256) s += __expf(lr[c]);
  for (int off = 32; off; off >>= 1) s += __shfl_down(s, off, 64);
  __shared__ float sred[4];
  int lane = t & 63, w = t >> 6;
  if (lane == 0) sred[w] = s;
  __syncthreads();
  if (t == 0) {
    float tot = sred[0] + sred[1] + sred[2] + sred[3];
    float ce = logf(tot) - lr[labels[row]];
    atomicAdd(accums, ce);
  }
}

// ---------------- final: SCL assembly + loss ----------------
__global__ void final_kernel(const float* __restrict__ S, const float* __restrict__ P,
                             const int* __restrict__ labels, const int* __restrict__ hist,
                             const float* __restrict__ accums, float* __restrict__ out) {
  int t = threadIdx.x;
  float lsum = 0.0f, lval = 0.0f;
  for (int i = t; i < N; i += 256) {
    int cnt = hist[labels[i]] - 1;
    if (cnt > 0) {
      float bl = logf(S[i]);
      float per = -(P[i] - (float)cnt * bl) / (float)cnt;
      lsum += per;
      lval += 1.0f;
    }
  }
  for (int off = 32; off; off >>= 1) {
    lsum += __shfl_down(lsum, off, 64);
    lval += __shfl_down(lval, off, 64);
  }
  __shared__ float ss[4], sv[4];
  int lane = t & 63, w = t >> 6;
  if (lane == 0) { ss[w] = lsum; sv[w] = lval; }
  __syncthreads();
  if (t == 0) {
    float sum = ss[0] + ss[1] + ss[2] + ss[3];
    float nv = sv[0] + sv[1] + sv[2] + sv[3];
    float scl = (nv > 0.0f) ? sum / nv : 0.0f;
    float ce = accums[0] * (1.0f / (float)N);
    out[(size_t)N * C] = 0.9f * ce + 0.1f * scl;
  }
}

extern "C" void kernel_launch(void* const* d_in, const int* in_sizes, int n_in,
                              void* d_out, int out_size, void* d_ws, size_t ws_size,
                              hipStream_t stream) {
  const float* feat   = (const float*)d_in[0];
  const int*   labels = (const int*)d_in[1];
  const float* W      = (const float*)d_in[2];
  const float* b      = (const float*)d_in[3];
  float* out = (float*)d_out;  // [N*C logits, 1 loss]

  char* ws = (char*)d_ws;
  bf16_t* feat_n = (bf16_t*)ws;                                   // N*D*2  = 16.78 MB
  bf16_t* Wp     = (bf16_t*)(ws + (size_t)N * D * 2);             // CP*D*2 =  2.10 MB
  float*  norms  = (float*)(ws + (size_t)N * D * 2 + (size_t)CP * D * 2);
  float*  S      = norms + N;
  float*  P      = S + N;
  int*    hist   = (int*)(P + N);                                  // 1024 ints
  float*  accums = (float*)(hist + 1024);

  // zero the accumulator region (S, P, hist, accums are contiguous)
  size_t zero_bytes = (size_t)((char*)(accums + 16) - (char*)S);
  hipMemsetAsync(S, 0, zero_bytes, stream);

  normalize_kernel<<<N, 256, 0, stream>>>(feat, norms, feat_n);
  castw_kernel<<<CP, 256, 0, stream>>>(W, Wp);
  hist_kernel<<<N / 256, 256, 0, stream>>>(labels, hist);
  logits_gemm<<<dim3(N / BM, CP / BN), 256, 0, stream>>>(feat_n, Wp, norms, b, out);
  sim_gemm<<<dim3(N / BM, N / BN), 256, 0, stream>>>(feat_n, labels, S, P);
  ce_kernel<<<N, 256, 0, stream>>>(out, labels, accums);
  final_kernel<<<1, 256, 0, stream>>>(S, P, labels, hist, accums, out);
}

// Round 2
// 386.479 us; speedup vs baseline: 1.2116x; 1.2116x over previous
//
#include <hip/hip_runtime.h>
#include <hip/hip_bf16.h>
#include <math.h>

#define N 8192
#define D 1024
#define C 1000
#define CP 1024
#define INV_T (1.0f / 0.3f)

typedef __bf16 bf16_t;
typedef bf16_t bf16x8 __attribute__((ext_vector_type(8)));
typedef float f32x4 __attribute__((ext_vector_type(4)));

typedef __attribute__((address_space(3))) uint32_t lds_u32_t;
typedef const __attribute__((address_space(1))) uint32_t glb_u32_t;

// ---------------- normalize: feat -> feat_n (bf16), norms (f32) ----------------
__global__ void normalize_kernel(const float* __restrict__ feat,
                                 float* __restrict__ norms,
                                 bf16_t* __restrict__ feat_n) {
  int row = blockIdx.x;
  int t = threadIdx.x;  // 256 threads, each handles 4 consecutive floats
  const float4* fr = (const float4*)(feat + (size_t)row * D);
  float4 x = fr[t];
  float ss = x.x * x.x + x.y * x.y + x.z * x.z + x.w * x.w;
  for (int off = 32; off; off >>= 1) ss += __shfl_down(ss, off, 64);
  __shared__ float sred[4];
  __shared__ float srn;
  int lane = t & 63, w = t >> 6;
  if (lane == 0) sred[w] = ss;
  __syncthreads();
  if (t == 0) {
    float tot = sred[0] + sred[1] + sred[2] + sred[3];
    float nrm = sqrtf(tot);
    norms[row] = nrm;
    srn = 1.0f / nrm;
  }
  __syncthreads();
  float rn = srn;
  union { bf16_t h[4]; uint2 u; } pk;
  pk.h[0] = (bf16_t)(x.x * rn);
  pk.h[1] = (bf16_t)(x.y * rn);
  pk.h[2] = (bf16_t)(x.z * rn);
  pk.h[3] = (bf16_t)(x.w * rn);
  *(uint2*)(feat_n + (size_t)row * D + t * 4) = pk.u;
}

// ---------------- cast W (f32 [C,D]) -> Wp (bf16 [CP,D], zero-padded) ----------------
__global__ void castw_kernel(const float* __restrict__ W, bf16_t* __restrict__ Wp) {
  int idx = blockIdx.x * 256 + threadIdx.x;
  int row = idx >> 8;
  int c4 = (idx & 255) << 2;
  union { bf16_t h[4]; uint2 u; } pk;
  if (row < C) {
    float4 x = ((const float4*)(W + (size_t)row * D))[idx & 255];
    pk.h[0] = (bf16_t)x.x; pk.h[1] = (bf16_t)x.y;
    pk.h[2] = (bf16_t)x.z; pk.h[3] = (bf16_t)x.w;
  } else {
    pk.h[0] = pk.h[1] = pk.h[2] = pk.h[3] = (bf16_t)0.0f;
  }
  *(uint2*)(Wp + (size_t)row * D + c4) = pk.u;
}

// ---------------- label histogram ----------------
__global__ void hist_kernel(const int* __restrict__ labels, int* __restrict__ hist) {
  int i = blockIdx.x * 256 + threadIdx.x;
  if (i < N) atomicAdd(&hist[labels[i]], 1);
}

// ---------------- GEMM tile geometry ----------------
#define BM 128
#define BN 128
#define BK 32
// LDS tile: 128 rows x 32 bf16 = 8192 B = 512 chunks of 16 B, NO padding
// (global_load_lds dest is wave-uniform base + lane*16). Conflicts killed by
// XOR chunk swizzle: chunk c of row r lives at c ^ ((r>>1)&3); frag-read
// bank-quad = (4r + c') mod 8 -> rows 0..7 cover all 8 quads, 2-way = free.

// stage one 128x32 bf16 tile: g0 = &src[tile_row0 * D + k0]
__device__ __forceinline__ void stage_tile(const bf16_t* __restrict__ g0,
                                           bf16_t* lds, int t, int w) {
#pragma unroll
  for (int p = 0; p < 2; p++) {
    int chunk = p * 256 + t;           // 0..511
    int r = chunk >> 2;                // tile row 0..127
    int c = (chunk & 3) ^ ((r >> 1) & 3);  // global 16B-chunk within row
    const bf16_t* gp = g0 + (size_t)r * D + c * 8;
    bf16_t* lp = lds + (size_t)(p * 256 + w * 64) * 8;  // wave-uniform base
    __builtin_amdgcn_global_load_lds((glb_u32_t*)gp, (lds_u32_t*)lp, 16, 0, 0);
  }
}

// logits[i,c] = norms[i] * (feat_n[i,:] . Wp[c,:]) + b[c]
__launch_bounds__(256)
__global__ void logits_gemm(const bf16_t* __restrict__ A, const bf16_t* __restrict__ B,
                            const float* __restrict__ norms, const float* __restrict__ bias,
                            float* __restrict__ out) {
  __shared__ __align__(16) bf16_t As[BM * BK];
  __shared__ __align__(16) bf16_t Bs[BN * BK];
  int tileM = blockIdx.x * BM;
  int tileN = blockIdx.y * BN;
  int t = threadIdx.x;
  int lane = t & 63;
  int w = t >> 6;
  int wm = (w & 1) << 6;
  int wn = (w >> 1) << 6;
  int l15 = lane & 15;
  int quad = lane >> 4;
  f32x4 acc[4][4] = {};
  const bf16_t* Abase = A + (size_t)tileM * D;
  const bf16_t* Bbase = B + (size_t)tileN * D;
  for (int k0 = 0; k0 < D; k0 += BK) {
    stage_tile(Abase + k0, As, t, w);
    stage_tile(Bbase + k0, Bs, t, w);
    __syncthreads();
    bf16x8 af[4], bfr[4];
#pragma unroll
    for (int i = 0; i < 4; i++) {
      int ar = wm + i * 16 + l15;
      int cc = quad ^ ((ar >> 1) & 3);
      af[i] = *(const bf16x8*)(&As[ar * BK + cc * 8]);
    }
#pragma unroll
    for (int j = 0; j < 4; j++) {
      int br = wn + j * 16 + l15;
      int cc = quad ^ ((br >> 1) & 3);
      bfr[j] = *(const bf16x8*)(&Bs[br * BK + cc * 8]);
    }
#pragma unroll
    for (int i = 0; i < 4; i++)
#pragma unroll
      for (int j = 0; j < 4; j++)
        acc[i][j] = __builtin_amdgcn_mfma_f32_16x16x32_bf16(af[i], bfr[j], acc[i][j], 0, 0, 0);
    __syncthreads();
  }
#pragma unroll
  for (int i = 0; i < 4; i++) {
#pragma unroll
    for (int r = 0; r < 4; r++) {
      int gr = tileM + wm + i * 16 + quad * 4 + r;
      float nrm = norms[gr];
#pragma unroll
      for (int j = 0; j < 4; j++) {
        int gc = tileN + wn + j * 16 + l15;
        if (gc < C) out[(size_t)gr * C + gc] = nrm * acc[i][j][r] + bias[gc];
      }
    }
  }
}

// sim tile = (feat_n @ feat_n^T)/t on upper-triangle blocks only; fused:
//   S[i] += sum_{j != i} exp(sim_ij) ; P[i] += sum_{j: lbl==, j!=i} sim_ij
// off-diagonal blocks also push column sums (symmetry).
__launch_bounds__(256)
__global__ void sim_gemm(const bf16_t* __restrict__ A, const int* __restrict__ labels,
                         float* __restrict__ S, float* __restrict__ P) {
  __shared__ __align__(16) bf16_t As[BM * BK];
  __shared__ __align__(16) bf16_t Bs[BN * BK];
  // decode upper-triangle block index (row-major incl. diagonal), nb = 64
  int g = blockIdx.x;
  const int nb = N / BM;
  float fnb = (float)nb + 0.5f;
  int bi = (int)(fnb - sqrtf(fnb * fnb - 2.0f * (float)g));
  if (bi < 0) bi = 0;
#define TRI_OFF(r) ((r) * nb - (r) * ((r)-1) / 2)
  while (TRI_OFF(bi + 1) <= g) bi++;
  while (TRI_OFF(bi) > g) bi--;
  int bj = bi + (g - TRI_OFF(bi));
#undef TRI_OFF
  int tileM = bi * BM;
  int tileN = bj * BN;
  bool diag = (bi == bj);

  int t = threadIdx.x;
  int lane = t & 63;
  int w = t >> 6;
  int wm = (w & 1) << 6;
  int wn = (w >> 1) << 6;
  int l15 = lane & 15;
  int quad = lane >> 4;
  f32x4 acc[4][4] = {};
  const bf16_t* Abase = A + (size_t)tileM * D;
  const bf16_t* Bbase = A + (size_t)tileN * D;
  for (int k0 = 0; k0 < D; k0 += BK) {
    stage_tile(Abase + k0, As, t, w);
    stage_tile(Bbase + k0, Bs, t, w);
    __syncthreads();
    bf16x8 af[4], bfr[4];
#pragma unroll
    for (int i = 0; i < 4; i++) {
      int ar = wm + i * 16 + l15;
      int cc = quad ^ ((ar >> 1) & 3);
      af[i] = *(const bf16x8*)(&As[ar * BK + cc * 8]);
    }
#pragma unroll
    for (int j = 0; j < 4; j++) {
      int br = wn + j * 16 + l15;
      int cc = quad ^ ((br >> 1) & 3);
      bfr[j] = *(const bf16x8*)(&Bs[br * BK + cc * 8]);
    }
#pragma unroll
    for (int i = 0; i < 4; i++)
#pragma unroll
      for (int j = 0; j < 4; j++)
        acc[i][j] = __builtin_amdgcn_mfma_f32_16x16x32_bf16(af[i], bfr[j], acc[i][j], 0, 0, 0);
    __syncthreads();
  }
  // fused epilogue
  int gcj[4], lc[4];
#pragma unroll
  for (int j = 0; j < 4; j++) {
    gcj[j] = tileN + wn + j * 16 + l15;
    lc[j] = labels[gcj[j]];
  }
  float csS[4] = {0.f, 0.f, 0.f, 0.f}, csP[4] = {0.f, 0.f, 0.f, 0.f};
#pragma unroll
  for (int i = 0; i < 4; i++) {
#pragma unroll
    for (int r = 0; r < 4; r++) {
      int gr = tileM + wm + i * 16 + quad * 4 + r;
      int lr = labels[gr];
      float ssum = 0.0f, psum = 0.0f;
#pragma unroll
      for (int j = 0; j < 4; j++) {
        float sim = acc[i][j][r] * INV_T;
        if (gcj[j] != gr) {
          float e = __expf(sim);
          float pv = (lc[j] == lr) ? sim : 0.0f;
          ssum += e;
          psum += pv;
          csS[j] += e;
          csP[j] += pv;
        }
      }
      // row reduce across the 16 column-lanes of this quad
      for (int m = 1; m < 16; m <<= 1) {
        ssum += __shfl_xor(ssum, m, 64);
        psum += __shfl_xor(psum, m, 64);
      }
      if (l15 == 0) {
        atomicAdd(&S[gr], ssum);
        atomicAdd(&P[gr], psum);
      }
    }
  }
  if (!diag) {
    // column sums: reduce across the 4 quads (lanes sharing l15): xor 16, 32
#pragma unroll
    for (int j = 0; j < 4; j++) {
      csS[j] += __shfl_xor(csS[j], 16, 64);
      csS[j] += __shfl_xor(csS[j], 32, 64);
      csP[j] += __shfl_xor(csP[j], 16, 64);
      csP[j] += __shfl_xor(csP[j], 32, 64);
      if (quad == 0) {
        atomicAdd(&S[gcj[j]], csS[j]);
        atomicAdd(&P[gcj[j]], csP[j]);
      }
    }
  }
}

// ---------------- CE: per-row logsumexp - label logit, atomically summed ----------------
__global__ void ce_kernel(const float* __restrict__ logits, const int* __restrict__ labels,
                          float* __restrict__ accums) {
  int row = blockIdx.x;
  const float* lr = logits + (size_t)row * C;
  int t = threadIdx.x;
  float s = 0.0f;
  for (int c = t; c < C; c += 256) s += __expf(lr[c]);
  for (int off = 32; off; off >>= 1) s += __shfl_down(s, off, 64);
  __shared__ float sred[4];
  int lane = t & 63, w = t >> 6;
  if (lane == 0) sred[w] = s;
  __syncthreads();
  if (t == 0) {
    float tot = sred[0] + sred[1] + sred[2] + sred[3];
    float ce = logf(tot) - lr[labels[row]];
    atomicAdd(accums, ce);
  }
}

// ---------------- final: SCL assembly + loss ----------------
__global__ void final_kernel(const float* __restrict__ S, const float* __restrict__ P,
                             const int* __restrict__ labels, const int* __restrict__ hist,
                             const float* __restrict__ accums, float* __restrict__ out) {
  int t = threadIdx.x;
  float lsum = 0.0f, lval = 0.0f;
  for (int i = t; i < N; i += 256) {
    int cnt = hist[labels[i]] - 1;
    if (cnt > 0) {
      float bl = logf(S[i]);
      float per = -(P[i] - (float)cnt * bl) / (float)cnt;
      lsum += per;
      lval += 1.0f;
    }
  }
  for (int off = 32; off; off >>= 1) {
    lsum += __shfl_down(lsum, off, 64);
    lval += __shfl_down(lval, off, 64);
  }
  __shared__ float ss[4], sv[4];
  int lane = t & 63, w = t >> 6;
  if (lane == 0) { ss[w] = lsum; sv[w] = lval; }
  __syncthreads();
  if (t == 0) {
    float sum = ss[0] + ss[1] + ss[2] + ss[3];
    float nv = sv[0] + sv[1] + sv[2] + sv[3];
    float scl = (nv > 0.0f) ? sum / nv : 0.0f;
    float ce = accums[0] * (1.0f / (float)N);
    out[(size_t)N * C] = 0.9f * ce + 0.1f * scl;
  }
}

extern "C" void kernel_launch(void* const* d_in, const int* in_sizes, int n_in,
                              void* d_out, int out_size, void* d_ws, size_t ws_size,
                              hipStream_t stream) {
  const float* feat   = (const float*)d_in[0];
  const int*   labels = (const int*)d_in[1];
  const float* W      = (const float*)d_in[2];
  const float* b      = (const float*)d_in[3];
  float* out = (float*)d_out;  // [N*C logits, 1 loss]

  char* ws = (char*)d_ws;
  bf16_t* feat_n = (bf16_t*)ws;                                   // N*D*2  = 16.78 MB
  bf16_t* Wp     = (bf16_t*)(ws + (size_t)N * D * 2);             // CP*D*2 =  2.10 MB
  float*  norms  = (float*)(ws + (size_t)N * D * 2 + (size_t)CP * D * 2);
  float*  S      = norms + N;
  float*  P      = S + N;
  int*    hist   = (int*)(P + N);                                  // 1024 ints
  float*  accums = (float*)(hist + 1024);

  // zero the accumulator region (S, P, hist, accums are contiguous)
  size_t zero_bytes = (size_t)((char*)(accums + 16) - (char*)S);
  hipMemsetAsync(S, 0, zero_bytes, stream);

  normalize_kernel<<<N, 256, 0, stream>>>(feat, norms, feat_n);
  castw_kernel<<<CP, 256, 0, stream>>>(W, Wp);
  hist_kernel<<<N / 256, 256, 0, stream>>>(labels, hist);
  logits_gemm<<<dim3(N / BM, CP / BN), 256, 0, stream>>>(feat_n, Wp, norms, b, out);
  const int nb = N / BM;
  sim_gemm<<<nb * (nb + 1) / 2, 256, 0, stream>>>(feat_n, labels, S, P);
  ce_kernel<<<N, 256, 0, stream>>>(out, labels, accums);
  final_kernel<<<1, 256, 0, stream>>>(S, P, labels, hist, accums, out);
}

// Round 3
// 319.051 us; speedup vs baseline: 1.4676x; 1.2113x over previous
//
#include <hip/hip_runtime.h>
#include <hip/hip_bf16.h>
#include <math.h>

#define N 8192
#define D 1024
#define C 1000
#define CP 1024
#define INV_T (1.0f / 0.3f)

typedef __bf16 bf16_t;
typedef bf16_t bf16x8 __attribute__((ext_vector_type(8)));
typedef float f32x4 __attribute__((ext_vector_type(4)));

typedef __attribute__((address_space(3))) uint32_t lds_u32_t;
typedef const __attribute__((address_space(1))) uint32_t glb_u32_t;

// ---------------- prep: normalize rows (+hist) and cast W, one dispatch ----------------
// g < N: normalize row g of feat -> feat_n (bf16) + norms; thread0 hist atomic.
// g >= N: cast row (g-N) of W -> Wp (bf16, zero-padded to CP rows).
__global__ void prep_kernel(const float* __restrict__ feat, const int* __restrict__ labels,
                            const float* __restrict__ W,
                            float* __restrict__ norms, bf16_t* __restrict__ feat_n,
                            bf16_t* __restrict__ Wp, int* __restrict__ hist) {
  int g = blockIdx.x;
  int t = threadIdx.x;
  if (g < N) {
    int row = g;
    const float4* fr = (const float4*)(feat + (size_t)row * D);
    float4 x = fr[t];
    float ss = x.x * x.x + x.y * x.y + x.z * x.z + x.w * x.w;
    for (int off = 32; off; off >>= 1) ss += __shfl_down(ss, off, 64);
    __shared__ float sred[4];
    __shared__ float srn;
    int lane = t & 63, w = t >> 6;
    if (lane == 0) sred[w] = ss;
    __syncthreads();
    if (t == 0) {
      float tot = sred[0] + sred[1] + sred[2] + sred[3];
      float nrm = sqrtf(tot);
      norms[row] = nrm;
      srn = 1.0f / nrm;
      atomicAdd(&hist[labels[row]], 1);
    }
    __syncthreads();
    float rn = srn;
    union { bf16_t h[4]; uint2 u; } pk;
    pk.h[0] = (bf16_t)(x.x * rn);
    pk.h[1] = (bf16_t)(x.y * rn);
    pk.h[2] = (bf16_t)(x.z * rn);
    pk.h[3] = (bf16_t)(x.w * rn);
    *(uint2*)(feat_n + (size_t)row * D + t * 4) = pk.u;
  } else {
    int row = g - N;
    union { bf16_t h[4]; uint2 u; } pk;
    if (row < C) {
      float4 x = ((const float4*)(W + (size_t)row * D))[t];
      pk.h[0] = (bf16_t)x.x; pk.h[1] = (bf16_t)x.y;
      pk.h[2] = (bf16_t)x.z; pk.h[3] = (bf16_t)x.w;
    } else {
      pk.h[0] = pk.h[1] = pk.h[2] = pk.h[3] = (bf16_t)0.0f;
    }
    *(uint2*)(Wp + (size_t)row * D + t * 4) = pk.u;
  }
}

// ---------------- GEMM tile geometry ----------------
#define BM 128
#define BN 128
#define BK 64
#define NSIM 2080   // 64*65/2 upper-triangle blocks
#define NLOG 512    // 64 x 8 logits blocks
// LDS tile: 128 rows x 64 bf16 = 16 KB = 1024 chunks of 16 B, NO padding
// (global_load_lds dest = wave-uniform base + lane*16). XOR chunk swizzle:
// global chunk c of row r lives at slot c ^ (r & 7); frag-read bank-quad
// spread = 2-way max (free, m136). Measured 0 conflicts with the 4-chunk
// variant in R2; same math here with 8 chunks.

__device__ __forceinline__ void stage_tile(const bf16_t* __restrict__ g0,
                                           bf16_t* lds, int t, int w) {
#pragma unroll
  for (int p = 0; p < 4; p++) {
    int chunk = p * 256 + t;           // 0..1023
    int r = chunk >> 3;                // tile row 0..127
    int c = (chunk & 7) ^ (r & 7);     // global 16B-chunk within row
    const bf16_t* gp = g0 + (size_t)r * D + c * 8;
    bf16_t* lp = lds + (size_t)(p * 256 + w * 64) * 8;  // wave-uniform base
    __builtin_amdgcn_global_load_lds((glb_u32_t*)gp, (lds_u32_t*)lp, 16, 0, 0);
  }
}

// one fused kernel: g < NSIM -> sim block (upper triangle), else logits block
__launch_bounds__(256)
__global__ void mega_gemm(const bf16_t* __restrict__ A, const bf16_t* __restrict__ Wp,
                          const int* __restrict__ labels,
                          const float* __restrict__ norms, const float* __restrict__ bias,
                          float* __restrict__ S, float* __restrict__ P,
                          float* __restrict__ out) {
  __shared__ __align__(16) bf16_t As[BM * BK];
  __shared__ __align__(16) bf16_t Bs[BN * BK];
  int g = blockIdx.x;
  int t = threadIdx.x;
  int lane = t & 63;
  int w = t >> 6;
  int wm = (w & 1) << 6;
  int wn = (w >> 1) << 6;
  int l15 = lane & 15;
  int quad = lane >> 4;
  f32x4 acc[4][4] = {};

  bool is_sim = (g < NSIM);
  int tileM, tileN;
  bool diag = false;
  if (is_sim) {
    const int nb = N / BM;
    float fnb = (float)nb + 0.5f;
    int bi = (int)(fnb - sqrtf(fnb * fnb - 2.0f * (float)g));
    if (bi < 0) bi = 0;
#define TRI_OFF(r) ((r) * nb - (r) * ((r)-1) / 2)
    while (TRI_OFF(bi + 1) <= g) bi++;
    while (TRI_OFF(bi) > g) bi--;
    int bj = bi + (g - TRI_OFF(bi));
#undef TRI_OFF
    tileM = bi * BM;
    tileN = bj * BN;
    diag = (bi == bj);
  } else {
    int lg = g - NSIM;
    tileM = (lg >> 3) * BM;   // 0..63
    tileN = (lg & 7) * BN;    // 0..7
  }

  const bf16_t* Abase = A + (size_t)tileM * D;
  const bf16_t* Bbase = (is_sim ? A : Wp) + (size_t)tileN * D;

  for (int k0 = 0; k0 < D; k0 += BK) {
    stage_tile(Abase + k0, As, t, w);
    stage_tile(Bbase + k0, Bs, t, w);
    __syncthreads();
#pragma unroll
    for (int h = 0; h < 2; h++) {
      bf16x8 af[4], bfr[4];
#pragma unroll
      for (int i = 0; i < 4; i++) {
        int ar = wm + i * 16 + l15;
        int cc = (h * 4 + quad) ^ (ar & 7);
        af[i] = *(const bf16x8*)(&As[ar * BK + cc * 8]);
      }
#pragma unroll
      for (int j = 0; j < 4; j++) {
        int br = wn + j * 16 + l15;
        int cc = (h * 4 + quad) ^ (br & 7);
        bfr[j] = *(const bf16x8*)(&Bs[br * BK + cc * 8]);
      }
#pragma unroll
      for (int i = 0; i < 4; i++)
#pragma unroll
        for (int j = 0; j < 4; j++)
          acc[i][j] = __builtin_amdgcn_mfma_f32_16x16x32_bf16(af[i], bfr[j], acc[i][j], 0, 0, 0);
    }
    __syncthreads();
  }

  if (is_sim) {
    // fused epilogue: S[i] += sum_{j!=i} exp(sim_ij); P[i] += sum_{pos} sim_ij
    // off-diagonal blocks also push column sums (symmetry).
    int gcj[4], lc[4];
#pragma unroll
    for (int j = 0; j < 4; j++) {
      gcj[j] = tileN + wn + j * 16 + l15;
      lc[j] = labels[gcj[j]];
    }
    float csS[4] = {0.f, 0.f, 0.f, 0.f}, csP[4] = {0.f, 0.f, 0.f, 0.f};
#pragma unroll
    for (int i = 0; i < 4; i++) {
#pragma unroll
      for (int r = 0; r < 4; r++) {
        int gr = tileM + wm + i * 16 + quad * 4 + r;
        int lr = labels[gr];
        float ssum = 0.0f, psum = 0.0f;
#pragma unroll
        for (int j = 0; j < 4; j++) {
          float sim = acc[i][j][r] * INV_T;
          if (gcj[j] != gr) {
            float e = __expf(sim);
            float pv = (lc[j] == lr) ? sim : 0.0f;
            ssum += e;
            psum += pv;
            csS[j] += e;
            csP[j] += pv;
          }
        }
        for (int m = 1; m < 16; m <<= 1) {
          ssum += __shfl_xor(ssum, m, 64);
          psum += __shfl_xor(psum, m, 64);
        }
        if (l15 == 0) {
          atomicAdd(&S[gr], ssum);
          atomicAdd(&P[gr], psum);
        }
      }
    }
    if (!diag) {
#pragma unroll
      for (int j = 0; j < 4; j++) {
        csS[j] += __shfl_xor(csS[j], 16, 64);
        csS[j] += __shfl_xor(csS[j], 32, 64);
        csP[j] += __shfl_xor(csP[j], 16, 64);
        csP[j] += __shfl_xor(csP[j], 32, 64);
        if (quad == 0) {
          atomicAdd(&S[gcj[j]], csS[j]);
          atomicAdd(&P[gcj[j]], csP[j]);
        }
      }
    }
  } else {
#pragma unroll
    for (int i = 0; i < 4; i++) {
#pragma unroll
      for (int r = 0; r < 4; r++) {
        int gr = tileM + wm + i * 16 + quad * 4 + r;
        float nrm = norms[gr];
#pragma unroll
        for (int j = 0; j < 4; j++) {
          int gc = tileN + wn + j * 16 + l15;
          if (gc < C) out[(size_t)gr * C + gc] = nrm * acc[i][j][r] + bias[gc];
        }
      }
    }
  }
}

// ---------------- CE: per-row logsumexp - label logit -> ce_row (NO atomics) ----------------
__global__ void ce_kernel(const float* __restrict__ logits, const int* __restrict__ labels,
                          float* __restrict__ ce_row) {
  int row = blockIdx.x;
  const float* lr = logits + (size_t)row * C;
  int t = threadIdx.x;
  float s = 0.0f;
  for (int c = t; c < C; c += 256) s += __expf(lr[c]);
  for (int off = 32; off; off >>= 1) s += __shfl_down(s, off, 64);
  __shared__ float sred[4];
  int lane = t & 63, w = t >> 6;
  if (lane == 0) sred[w] = s;
  __syncthreads();
  if (t == 0) {
    float tot = sred[0] + sred[1] + sred[2] + sred[3];
    ce_row[row] = logf(tot) - lr[labels[row]];
  }
}

// ---------------- final: CE mean + SCL assembly + loss ----------------
__global__ void final_kernel(const float* __restrict__ S, const float* __restrict__ P,
                             const int* __restrict__ labels, const int* __restrict__ hist,
                             const float* __restrict__ ce_row, float* __restrict__ out) {
  int t = threadIdx.x;
  float lsum = 0.0f, lval = 0.0f, cesum = 0.0f;
  for (int i = t; i < N; i += 256) {
    cesum += ce_row[i];
    int cnt = hist[labels[i]] - 1;
    if (cnt > 0) {
      float bl = logf(S[i]);
      float per = -(P[i] - (float)cnt * bl) / (float)cnt;
      lsum += per;
      lval += 1.0f;
    }
  }
  for (int off = 32; off; off >>= 1) {
    lsum += __shfl_down(lsum, off, 64);
    lval += __shfl_down(lval, off, 64);
    cesum += __shfl_down(cesum, off, 64);
  }
  __shared__ float ss[4], sv[4], sc[4];
  int lane = t & 63, w = t >> 6;
  if (lane == 0) { ss[w] = lsum; sv[w] = lval; sc[w] = cesum; }
  __syncthreads();
  if (t == 0) {
    float sum = ss[0] + ss[1] + ss[2] + ss[3];
    float nv = sv[0] + sv[1] + sv[2] + sv[3];
    float ce = (sc[0] + sc[1] + sc[2] + sc[3]) * (1.0f / (float)N);
    float scl = (nv > 0.0f) ? sum / nv : 0.0f;
    out[(size_t)N * C] = 0.9f * ce + 0.1f * scl;
  }
}

extern "C" void kernel_launch(void* const* d_in, const int* in_sizes, int n_in,
                              void* d_out, int out_size, void* d_ws, size_t ws_size,
                              hipStream_t stream) {
  const float* feat   = (const float*)d_in[0];
  const int*   labels = (const int*)d_in[1];
  const float* W      = (const float*)d_in[2];
  const float* b      = (const float*)d_in[3];
  float* out = (float*)d_out;  // [N*C logits, 1 loss]

  char* ws = (char*)d_ws;
  bf16_t* feat_n = (bf16_t*)ws;                                   // N*D*2  = 16.78 MB
  bf16_t* Wp     = (bf16_t*)(ws + (size_t)N * D * 2);             // CP*D*2 =  2.10 MB
  float*  norms  = (float*)(ws + (size_t)N * D * 2 + (size_t)CP * D * 2);
  float*  S      = norms + N;
  float*  P      = S + N;
  int*    hist   = (int*)(P + N);                                  // 1024 ints
  float*  ce_row = (float*)(hist + 1024);                          // N floats

  // zero S, P, hist (contiguous)
  size_t zero_bytes = (size_t)((char*)(hist + 1024) - (char*)S);
  hipMemsetAsync(S, 0, zero_bytes, stream);

  prep_kernel<<<N + CP, 256, 0, stream>>>(feat, labels, W, norms, feat_n, Wp, hist);
  mega_gemm<<<NSIM + NLOG, 256, 0, stream>>>(feat_n, Wp, labels, norms, b, S, P, out);
  ce_kernel<<<N, 256, 0, stream>>>(out, labels, ce_row);
  final_kernel<<<1, 256, 0, stream>>>(S, P, labels, hist, ce_row, out);
}